// Round 8
// baseline (1415.461 us; speedup 1.0000x reference)
//
#include <hip/hip_runtime.h>

// Problem constants (from reference)
#define NN 50000      // nodes
#define NE 300000     // edges
#define FEA 64        // edge feature dim
#define HD 256        // hidden
#define NG 256        // graphs
#define NL 4          // layers
#define OD 128        // out dim
#define SCB ((NN + 255) / 256)   // scan blocks = 196
#define NT ((NE + 63) / 64)      // 4688 edge tiles
#define EBLK 256                 // persistent edge blocks (1/CU)

typedef unsigned short u16;
typedef unsigned int u32;
typedef __attribute__((ext_vector_type(8))) short short8;
typedef __attribute__((ext_vector_type(4))) short s16x4;
typedef __attribute__((ext_vector_type(4))) float f32x4;

__device__ __forceinline__ u16 f2h(float f) {
    union { _Float16 h; u16 u; } v; v.h = (_Float16)f; return v.u;
}
__device__ __forceinline__ float h2f(u16 u) {
    union { u16 u; _Float16 h; } v; v.u = u; return (float)v.h;
}

// global -> LDS direct DMA, 16B per lane. LDS dest is wave-uniform base
// (HW adds lane*16); per-lane global source carries any swizzle (m104/m173).
typedef const __attribute__((address_space(1))) unsigned int gas_u32;
typedef __attribute__((address_space(3))) unsigned int las_u32;
__device__ __forceinline__ void gld16(const void* g, void* l) {
    __builtin_amdgcn_global_load_lds((gas_u32*)g, (las_u32*)l, 16, 0, 0);
}

// ---------------------------------------------------------------------------
// Persistent fused edge kernel: 256 blocks (1/CU, 160KB LDS), each loops
// ~18 tiles of 64 sorted edges x 256 cols.
//   W2 chunks 1..7 resident in LDS (staged ONCE per block) -> GEMM2 has no
//   per-tile weight staging; chunk 0 streams through SBUF which doubles as
//   the xh gather buffer. W1 + biases persistent in registers.
// LDS: W2L 112KB + SBUF 16KB + bufT 32KB = 163840 B (exactly 160 KiB).
// ---------------------------------------------------------------------------
__global__ __launch_bounds__(256, 1) void edge_k(
    const u16* __restrict__ eattrS, const u16* __restrict__ W1t,
    const float* __restrict__ bb1, const u16* __restrict__ W2t,
    const float* __restrict__ bb2,
    const int* __restrict__ srcI, const int* __restrict__ dstI,
    const u16* __restrict__ xh, float* __restrict__ aggr)
{
    __shared__ __align__(16) u16 W2L[7 * 8192];   // 114688 B: W2 chunks 1..7
    __shared__ __align__(16) u16 SBUF[8192];      // 16384 B: c0 / gather halves
    __shared__ __align__(16) u16 bufT[64 * 256];  // 32768 B: eattr->T1->msg
    const int tid = threadIdx.x;
    const int lane = tid & 63;
    const int w = tid >> 6;
    const int q = lane >> 4, c15 = lane & 15;
    const int wb = tid & ~63;      // wave-uniform lane-0 tid

    // ---- persistent register state ----
    // W1 fragments (direct-global layout validated rounds 5/6)
    short8 b1f[2][4];
#pragma unroll
    for (int s = 0; s < 2; ++s)
#pragma unroll
        for (int t = 0; t < 4; ++t) {
            const int nn = w * 64 + t * 16 + c15;
            b1f[s][t] = *(const short8*)(W1t + (size_t)nn * FEA + q * 8 + s * 32);
        }
    float4 b1v[4];
#pragma unroll
    for (int tm = 0; tm < 4; ++tm)
        b1v[tm] = *(const float4*)(bb1 + w * 64 + tm * 16 + q * 4);
    float b2f[4];
#pragma unroll
    for (int tn = 0; tn < 4; ++tn)
        b2f[tn] = bb2[w * 64 + tn * 16 + c15];

    // ---- stage W2 chunks 1..7 into W2L once (round-4 stageW2 layout) ----
    for (int cc = 1; cc < 8; ++cc) {
        const int k0c = cc * 32;
        u16* dst = &W2L[(cc - 1) * 8192];
#pragma unroll
        for (int it = 0; it < 4; ++it) {
            const int i = it * 256 + tid;
            const int n = i >> 2, j = i & 3;
            gld16(W2t + (size_t)n * HD + k0c + ((j ^ ((n >> 1) & 3)) * 8),
                  &dst[(it * 256 + wb) * 8]);
        }
    }
    // chunk 0 -> SBUF, eattr(tile0) -> bufT[0:8KB]
    {
#pragma unroll
        for (int it = 0; it < 4; ++it) {
            const int i = it * 256 + tid;
            const int n = i >> 2, j = i & 3;
            gld16(W2t + (size_t)n * HD + ((j ^ ((n >> 1) & 3)) * 8),
                  &SBUF[(it * 256 + wb) * 8]);
        }
        const int e00 = blockIdx.x * 64;
#pragma unroll
        for (int it = 0; it < 2; ++it) {
            const int i = it * 256 + tid;
            const int m = i >> 3, kb = i & 7;
            int row = e00 + m; if (row > NE - 1) row = NE - 1;
            gld16(eattrS + (size_t)row * FEA + ((kb ^ (m & 7)) * 8),
                  &bufT[(it * 256 + wb) * 8]);
        }
    }

    for (int tile = blockIdx.x; tile < NT; tile += EBLK) {
        const int e0 = tile * 64;
        __syncthreads();   // B1: eattr + c0 (+W2L on first iter) drained

        // GEMM1 (swapped): acc1[tm][tn] = C[W1col tile tm][edge tile tn]
        f32x4 acc1[4][4];
#pragma unroll
        for (int i = 0; i < 4; ++i)
#pragma unroll
            for (int j = 0; j < 4; ++j) acc1[i][j] = (f32x4)0.0f;
#pragma unroll
        for (int s = 0; s < 2; ++s) {
            short8 af[4];
#pragma unroll
            for (int t = 0; t < 4; ++t) {
                const int kga = s * 4 + q;
                const int mm = t * 16 + c15;
                af[t] = *(const short8*)&bufT[mm * 64 + ((kga ^ (mm & 7)) * 8)];
            }
            __builtin_amdgcn_s_setprio(1);
#pragma unroll
            for (int tm = 0; tm < 4; ++tm)
#pragma unroll
                for (int tn = 0; tn < 4; ++tn)
                    acc1[tm][tn] = __builtin_amdgcn_mfma_f32_16x16x32_f16(
                        b1f[s][tm], af[tn], acc1[tm][tn], 0, 0, 0);
            __builtin_amdgcn_s_setprio(0);
        }
        __syncthreads();   // B2: eattr consumed

        // T1 epi: pack 4 f16 along k, b64 write -> swizzled bufT[edge][256k]
#pragma unroll
        for (int tm = 0; tm < 4; ++tm) {
            const int kb = w * 8 + tm * 2 + (q >> 1);
#pragma unroll
            for (int tn = 0; tn < 4; ++tn) {
                const int edge = tn * 16 + c15;
                s16x4 o;
#pragma unroll
                for (int r = 0; r < 4; ++r) {
                    float v = acc1[tm][tn][r] + ((const float*)&b1v[tm])[r];
                    v = v > 0.0f ? v : 0.0f;
                    o[r] = (short)f2h(v);
                }
                *(s16x4*)((char*)bufT + edge * 512 +
                          ((kb ^ (edge & 7)) << 4) + ((q & 1) << 3)) = o;
            }
        }
        __syncthreads();   // B3: T1 visible (c0 drained at B1)

        // GEMM2: acc2 = T1 @ W2. Chunk 0 from SBUF, 1..7 from resident W2L.
        f32x4 acc2[4][4];
#pragma unroll
        for (int i = 0; i < 4; ++i)
#pragma unroll
            for (int j = 0; j < 4; ++j) acc2[i][j] = (f32x4)0.0f;
        {
            short8 af[4], bf[4];
#pragma unroll
            for (int t = 0; t < 4; ++t) {
                const int mm = t * 16 + c15;
                af[t] = *(const short8*)&bufT[mm * 256 + ((q ^ (mm & 7)) * 8)];
                const int nn = w * 64 + t * 16 + c15;
                bf[t] = *(const short8*)&SBUF[nn * 32 + ((q ^ ((nn >> 1) & 3)) * 8)];
            }
            __builtin_amdgcn_s_setprio(1);
#pragma unroll
            for (int tm = 0; tm < 4; ++tm)
#pragma unroll
                for (int tn = 0; tn < 4; ++tn)
                    acc2[tm][tn] = __builtin_amdgcn_mfma_f32_16x16x32_f16(
                        af[tm], bf[tn], acc2[tm][tn], 0, 0, 0);
            __builtin_amdgcn_s_setprio(0);
        }
        __syncthreads();   // Bc0: all waves done with SBUF chunk-0

        // issue gather-lo (rows 0..31) -> SBUF; hides under chunks 1..7
#pragma unroll
        for (int it = 0; it < 4; ++it) {
            const int i = it * 256 + tid;
            const int row = i >> 5, ch = i & 31;
            int er = e0 + row; if (er > NE - 1) er = NE - 1;
            const int sn = srcI[er];
            gld16(xh + (size_t)sn * HD + ch * 8, &SBUF[(it * 256 + wb) * 8]);
        }
        for (int c = 1; c < 8; ++c) {
            const u16* hp = &W2L[(c - 1) * 8192];
            short8 af[4], bf[4];
#pragma unroll
            for (int t = 0; t < 4; ++t) {
                const int mm = t * 16 + c15;
                const int kbg = c * 4 + q;
                af[t] = *(const short8*)&bufT[mm * 256 + ((kbg ^ (mm & 7)) * 8)];
                const int nn = w * 64 + t * 16 + c15;
                bf[t] = *(const short8*)&hp[nn * 32 + ((q ^ ((nn >> 1) & 3)) * 8)];
            }
            __builtin_amdgcn_s_setprio(1);
#pragma unroll
            for (int tm = 0; tm < 4; ++tm)
#pragma unroll
                for (int tn = 0; tn < 4; ++tn)
                    acc2[tm][tn] = __builtin_amdgcn_mfma_f32_16x16x32_f16(
                        af[tm], bf[tn], acc2[tm][tn], 0, 0, 0);
            __builtin_amdgcn_s_setprio(0);
        }
        __syncthreads();   // B4: T1 dead; gather-lo drained

        // msg-lo (rows 0..31): read SBUF, write col-major [col][32] to bufT-lo
#pragma unroll
        for (int tm = 0; tm < 2; ++tm) {
            const int rc = tm * 2 + (q >> 1);
#pragma unroll
            for (int tn = 0; tn < 4; ++tn) {
                const int col = w * 64 + tn * 16 + c15;
                s16x4 o;
#pragma unroll
                for (int r = 0; r < 4; ++r) {
                    const int rowL = tm * 16 + q * 4 + r;
                    float v = acc2[tm][tn][r] + b2f[tn] + h2f(SBUF[rowL * 256 + col]);
                    v = v > 0.0f ? v : 0.0f;
                    o[r] = (short)f2h(v);
                }
                *(s16x4*)((char*)bufT + col * 64 +
                          ((rc ^ (col & 3)) << 4) + ((q & 1) << 3)) = o;
            }
        }
        __syncthreads();   // B5: msg-lo visible; SBUF free

        // issue gather-hi (rows 32..63) -> SBUF; hides under segsum-lo
#pragma unroll
        for (int it = 0; it < 4; ++it) {
            const int i = it * 256 + tid;
            const int row = 32 + (i >> 5), ch = i & 31;
            int er = e0 + row; if (er > NE - 1) er = NE - 1;
            const int sn = srcI[er];
            gld16(xh + (size_t)sn * HD + ch * 8, &SBUF[(it * 256 + wb) * 8]);
        }
        // segsum-lo: thread = col, walk rows 0..31 via 4x short8
        {
            const char* part = (const char*)bufT;
            const int col = tid;
            float s = 0.0f;
            int cur = dstI[e0];   // e0 < NE always (tile < NT)
#pragma unroll
            for (int j = 0; j < 4; ++j) {
                short8 m8 = *(const short8*)(part + col * 64 + ((j ^ (col & 3)) << 4));
#pragma unroll
                for (int si = 0; si < 8; ++si) {
                    const int er = e0 + j * 8 + si;
                    const int d = (er < NE) ? dstI[er] : -1;
                    if (d != cur) {
                        if (cur >= 0 && s != 0.0f)
                            unsafeAtomicAdd(&aggr[(size_t)cur * HD + col], s);
                        cur = d; s = 0.0f;
                    }
                    s += h2f((u16)m8[si]);
                }
            }
            if (cur >= 0 && s != 0.0f)
                unsafeAtomicAdd(&aggr[(size_t)cur * HD + col], s);
        }
        __syncthreads();   // B6: gather-hi drained; segsum-lo done

        // msg-hi (rows 32..63) -> bufT-hi
#pragma unroll
        for (int tm = 2; tm < 4; ++tm) {
            const int rc = (tm - 2) * 2 + (q >> 1);
#pragma unroll
            for (int tn = 0; tn < 4; ++tn) {
                const int col = w * 64 + tn * 16 + c15;
                s16x4 o;
#pragma unroll
                for (int r = 0; r < 4; ++r) {
                    const int rowL = (tm - 2) * 16 + q * 4 + r;
                    float v = acc2[tm][tn][r] + b2f[tn] + h2f(SBUF[rowL * 256 + col]);
                    v = v > 0.0f ? v : 0.0f;
                    o[r] = (short)f2h(v);
                }
                *(s16x4*)((char*)bufT + 16384 + col * 64 +
                          ((rc ^ (col & 3)) << 4) + ((q & 1) << 3)) = o;
            }
        }
        __syncthreads();   // B7: msg-hi visible; SBUF free

        // prefetch next tile: chunk0 -> SBUF, eattr -> bufT[0:8KB]
        // (bufT-lo was last read by segsum-lo, done before B6)
        if (tile + EBLK < NT) {
#pragma unroll
            for (int it = 0; it < 4; ++it) {
                const int i = it * 256 + tid;
                const int n = i >> 2, j = i & 3;
                gld16(W2t + (size_t)n * HD + ((j ^ ((n >> 1) & 3)) * 8),
                      &SBUF[(it * 256 + wb) * 8]);
            }
            const int e0n = (tile + EBLK) * 64;
#pragma unroll
            for (int it = 0; it < 2; ++it) {
                const int i = it * 256 + tid;
                const int m = i >> 3, kb = i & 7;
                int row = e0n + m; if (row > NE - 1) row = NE - 1;
                gld16(eattrS + (size_t)row * FEA + ((kb ^ (m & 7)) * 8),
                      &bufT[(it * 256 + wb) * 8]);
            }
        }
        // segsum-hi: rows 32..63
        {
            const char* part = (const char*)bufT + 16384;
            const int col = tid;
            const int base = e0 + 32;
            float s = 0.0f;
            int cur = (base < NE) ? dstI[base] : -1;
#pragma unroll
            for (int j = 0; j < 4; ++j) {
                short8 m8 = *(const short8*)(part + col * 64 + ((j ^ (col & 3)) << 4));
#pragma unroll
                for (int si = 0; si < 8; ++si) {
                    const int er = base + j * 8 + si;
                    const int d = (er < NE) ? dstI[er] : -1;
                    if (d != cur) {
                        if (cur >= 0 && s != 0.0f)
                            unsafeAtomicAdd(&aggr[(size_t)cur * HD + col], s);
                        cur = d; s = 0.0f;
                    }
                    s += h2f((u16)m8[si]);
                }
            }
            if (cur >= 0 && s != 0.0f)
                unsafeAtomicAdd(&aggr[(size_t)cur * HD + col], s);
        }
    }
}

// ---------------------------------------------------------------------------
// Fused node kernel (exact round-4 version, validated at 1268 total).
// ---------------------------------------------------------------------------
__global__ __launch_bounds__(256, 2) void node_k(
    const u16* __restrict__ xh, const float* __restrict__ aggr,
    const float* __restrict__ epsv, int l,
    const u16* __restrict__ M1t, const float* __restrict__ mb1,
    const u16* __restrict__ M2t, const float* __restrict__ mb2,
    u16* __restrict__ hb, float* __restrict__ bns, float* __restrict__ bnq)
{
    __shared__ __align__(16) u16 bufW[256 * 64];   // 32768 B, 2x16KB halves
    __shared__ __align__(16) u16 bufT[64 * 256];   // 32768 B
    const int tid = threadIdx.x;
    const int lane = tid & 63;
    const int w = tid >> 6;
    const int q = lane >> 4, c15 = lane & 15;
    const int n0b = blockIdx.x * 64;
    const float e1 = 1.0f + epsv[l];
    const int wb = tid & ~63;

    auto stageM = [&](const u16* Mt, int cc) {
        const int k0c = cc * 32;
        const int hB = (cc & 1) * 1024;
#pragma unroll
        for (int it = 0; it < 4; ++it) {
            const int i = it * 256 + tid;
            const int n = i >> 2, j = i & 3;
            gld16(Mt + (size_t)n * HD + k0c + ((j ^ ((n >> 1) & 3)) * 8),
                  &bufW[(hB + it * 256 + wb) * 8]);
        }
    };
    stageM(M1t, 0);   // chunk-0 DMA flies under the A-tile build

    // stage A tile: h0 = (1+eps)*xh + aggr, 64 rows x 256 k, swizzled
#pragma unroll
    for (int it = 0; it < 8; ++it) {
        const int i = it * 256 + tid;        // 0..2047
        const int m = i >> 5, kb = i & 31;
        int row = n0b + m; if (row > NN - 1) row = NN - 1;
        const size_t base = (size_t)row * HD + kb * 8;
        short8 xv = *(const short8*)(xh + base);
        float4 a0 = *(const float4*)(aggr + base);
        float4 a1 = *(const float4*)(aggr + base + 4);
        u16 o[8];
        o[0] = f2h(e1 * h2f((u16)xv[0]) + a0.x);
        o[1] = f2h(e1 * h2f((u16)xv[1]) + a0.y);
        o[2] = f2h(e1 * h2f((u16)xv[2]) + a0.z);
        o[3] = f2h(e1 * h2f((u16)xv[3]) + a0.w);
        o[4] = f2h(e1 * h2f((u16)xv[4]) + a1.x);
        o[5] = f2h(e1 * h2f((u16)xv[5]) + a1.y);
        o[6] = f2h(e1 * h2f((u16)xv[6]) + a1.z);
        o[7] = f2h(e1 * h2f((u16)xv[7]) + a1.w);
        *(short8*)&bufT[m * 256 + ((kb ^ (m & 7)) * 8)] = *(short8*)o;
    }
    __syncthreads();

    // GEMM1 (swapped): acc1[tm][tn] -> C[m = M1col tile tm][n = node tile tn]
    f32x4 acc1[4][4];
#pragma unroll
    for (int i = 0; i < 4; ++i)
#pragma unroll
        for (int j = 0; j < 4; ++j) acc1[i][j] = (f32x4)0.0f;
#pragma unroll
    for (int c = 0; c < 8; ++c) {
        if (c < 7) stageM(M1t, c + 1);
        else       stageM(M2t, 0);     // prefetch GEMM2 chunk0 into free half0
        short8 af[4], bf[4];
        const u16* hp = &bufW[(c & 1) * 8192];
#pragma unroll
        for (int t = 0; t < 4; ++t) {
            const int mm = t * 16 + c15;
            const int kbg = c * 4 + q;
            af[t] = *(const short8*)&bufT[mm * 256 + ((kbg ^ (mm & 7)) * 8)];
            const int nn = w * 64 + t * 16 + c15;
            bf[t] = *(const short8*)&hp[nn * 32 + ((q ^ ((nn >> 1) & 3)) * 8)];
        }
        __builtin_amdgcn_s_setprio(1);
#pragma unroll
        for (int tm = 0; tm < 4; ++tm)
#pragma unroll
            for (int tn = 0; tn < 4; ++tn)
                acc1[tm][tn] = __builtin_amdgcn_mfma_f32_16x16x32_f16(
                    bf[tm], af[tn], acc1[tm][tn], 0, 0, 0);
        __builtin_amdgcn_s_setprio(0);
        __syncthreads();
    }

    // T2 epi: pack 4 f16 along k, b64 write into swizzled bufT[node][k]
    {
#pragma unroll
        for (int tm = 0; tm < 4; ++tm) {
            const float4 b1v = *(const float4*)(mb1 + w * 64 + tm * 16 + q * 4);
            const int kb = w * 8 + tm * 2 + (q >> 1);
#pragma unroll
            for (int tn = 0; tn < 4; ++tn) {
                const int node = tn * 16 + c15;
                s16x4 o;
#pragma unroll
                for (int r = 0; r < 4; ++r) {
                    float v = acc1[tm][tn][r] + ((const float*)&b1v)[r];
                    v = v > 0.0f ? v : 0.0f;
                    o[r] = (short)f2h(v);
                }
                *(s16x4*)((char*)bufT + node * 512 +
                          ((kb ^ (node & 7)) << 4) + ((q & 1) << 3)) = o;
            }
        }
    }
    __syncthreads();

    // GEMM2: acc2 = T2 @ M2 (not swapped): C[m=node][n=outcol]
    f32x4 acc2[4][4];
#pragma unroll
    for (int i = 0; i < 4; ++i)
#pragma unroll
        for (int j = 0; j < 4; ++j) acc2[i][j] = (f32x4)0.0f;
#pragma unroll
    for (int c = 0; c < 8; ++c) {
        if (c < 7) stageM(M2t, c + 1);
        short8 af[4], bf[4];
        const u16* hp = &bufW[(c & 1) * 8192];
#pragma unroll
        for (int t = 0; t < 4; ++t) {
            const int mm = t * 16 + c15;
            const int kbg = c * 4 + q;
            af[t] = *(const short8*)&bufT[mm * 256 + ((kbg ^ (mm & 7)) * 8)];
            const int nn = w * 64 + t * 16 + c15;
            bf[t] = *(const short8*)&hp[nn * 32 + ((q ^ ((nn >> 1) & 3)) * 8)];
        }
        __builtin_amdgcn_s_setprio(1);
#pragma unroll
        for (int tm = 0; tm < 4; ++tm)
#pragma unroll
            for (int tn = 0; tn < 4; ++tn)
                acc2[tm][tn] = __builtin_amdgcn_mfma_f32_16x16x32_f16(
                    af[tm], bf[tn], acc2[tm][tn], 0, 0, 0);
        __builtin_amdgcn_s_setprio(0);
        __syncthreads();
    }

    // EPI: hb = relu(acc2 + b2) store + BN stats
    float b2f[4];
#pragma unroll
    for (int tn = 0; tn < 4; ++tn)
        b2f[tn] = mb2[w * 64 + tn * 16 + c15];
    float ps[4] = {0, 0, 0, 0}, pq[4] = {0, 0, 0, 0};
#pragma unroll
    for (int tm = 0; tm < 4; ++tm) {
#pragma unroll
        for (int r = 0; r < 4; ++r) {
            const int grow = n0b + tm * 16 + q * 4 + r;
            if (grow < NN) {
#pragma unroll
                for (int tn = 0; tn < 4; ++tn) {
                    const int col = w * 64 + tn * 16 + c15;
                    float v = acc2[tm][tn][r] + b2f[tn];
                    v = v > 0.0f ? v : 0.0f;
                    hb[(size_t)grow * HD + col] = f2h(v);
                    ps[tn] += v; pq[tn] += v * v;
                }
            }
        }
    }
#pragma unroll
    for (int tn = 0; tn < 4; ++tn) {
        float s = ps[tn], sq = pq[tn];
        s += __shfl_down(s, 32, 64);  sq += __shfl_down(sq, 32, 64);
        s += __shfl_down(s, 16, 64);  sq += __shfl_down(sq, 16, 64);
        if (q == 0) {
            const int col = w * 64 + tn * 16 + c15;
            unsafeAtomicAdd(&bns[col], s);
            unsafeAtomicAdd(&bnq[col], sq);
        }
    }
}

// --------------------------- small helper kernels ---------------------------

// fp32 [L,K,N] -> fp16 transposed [L,N,K]
__global__ void transpose_k(const float* __restrict__ in, u16* __restrict__ oh,
                            int Kw, int Nw) {
    int i = blockIdx.x * blockDim.x + threadIdx.x;
    int tot = NL * Kw * Nw;
    if (i < tot) {
        int l = i / (Kw * Nw), rem = i % (Kw * Nw);
        int k = rem / Nw, n = rem % Nw;
        oh[(size_t)l * Kw * Nw + (size_t)n * Kw + k] = f2h(in[i]);
    }
}

__global__ void cvt_k(const float* __restrict__ in, u16* __restrict__ outh, int tot) {
    int i = blockIdx.x * blockDim.x + threadIdx.x;
    if (i < tot) outh[i] = f2h(in[i]);
}

// gather eattr rows into sorted order, fp32 -> fp16
__global__ void egather_k(const float* __restrict__ eattr, const int* __restrict__ perm,
                          u16* __restrict__ eattrS) {
    int i = blockIdx.x * blockDim.x + threadIdx.x;
    if (i < NE * FEA) {
        int row = i >> 6, k = i & 63;
        eattrS[i] = f2h(eattr[(size_t)perm[row] * FEA + k]);
    }
}

__global__ void zero_layer_k(float4* __restrict__ aggr4, float* __restrict__ bns,
                             float* __restrict__ bnq) {
    int i = blockIdx.x * blockDim.x + threadIdx.x;
    if (i < (NN * HD) / 4) aggr4[i] = make_float4(0.f, 0.f, 0.f, 0.f);
    if (i < HD) { bns[i] = 0.0f; bnq[i] = 0.0f; }
}

__global__ void zerof_k(float* __restrict__ p, int n) {
    int i = blockIdx.x * blockDim.x + threadIdx.x;
    if (i < n) p[i] = 0.0f;
}

// bnfin also zeroes bns/bnq for the next layer's node_k (runs before it)
__global__ void bnfin_k(float* __restrict__ bns, float* __restrict__ bnq,
                        const float* __restrict__ gamma, const float* __restrict__ beta,
                        int l, float* __restrict__ ab) {
    int c = threadIdx.x;
    float mu = bns[c] * (1.0f / (float)NN);
    float var = bnq[c] * (1.0f / (float)NN) - mu * mu;
    if (var < 0.0f) var = 0.0f;
    float a = gamma[l * HD + c] * rsqrtf(var + 1e-5f);
    float b = beta[l * HD + c] - mu * a;
    ab[c] = a; ab[HD + c] = b;
    bns[c] = 0.0f; bnq[c] = 0.0f;
}

// BN-apply fused with graph mean-pool accumulation + aggr zeroing for the
// next layer (batch sorted; run-reduction + 1 atomic per run).
__global__ void bnapply_k(const u16* __restrict__ hb, const float* __restrict__ ab,
                          const int* __restrict__ batch, u16* __restrict__ xh,
                          float* __restrict__ pooled, int l,
                          float* __restrict__ aggr, int zero_aggr) {
    const int t = threadIdx.x;
    const int n0 = blockIdx.x * 64;
    const float a = ab[t], b = ab[HD + t];
    const int hi = (NN - n0 < 64) ? (NN - n0) : 64;
    float s = 0.0f;
    int cur = batch[n0];
    for (int r = 0; r < hi; ++r) {
        const size_t idx = (size_t)(n0 + r) * HD + t;
        float v = a * h2f(hb[idx]) + b;
        xh[idx] = f2h(v);
        if (zero_aggr) aggr[idx] = 0.0f;
        const int g = batch[n0 + r];
        if (g != cur) {
            unsafeAtomicAdd(&pooled[(size_t)cur * (NL * HD) + l * HD + t], s);
            s = 0.0f; cur = g;
        }
        s += v;
    }
    unsafeAtomicAdd(&pooled[(size_t)cur * (NL * HD) + l * HD + t], s);
}

// ---- edge counting-sort by dst (hierarchical scan) ----

__global__ void zeroi_k(int* __restrict__ a, int n) {
    int i = blockIdx.x * blockDim.x + threadIdx.x;
    if (i < n) a[i] = 0;
}

__global__ void hist_k(const int* __restrict__ dst, int* __restrict__ hist) {
    int e = blockIdx.x * blockDim.x + threadIdx.x;
    if (e < NE) atomicAdd(&hist[dst[e]], 1);
}

__global__ void sumblk_k(const int* __restrict__ hist, int* __restrict__ psum) {
    __shared__ int red[256];
    int b = blockIdx.x, t = threadIdx.x, i = b * 256 + t;
    red[t] = (i < NN) ? hist[i] : 0;
    __syncthreads();
    for (int o = 128; o > 0; o >>= 1) {
        if (t < o) red[t] += red[t + o];
        __syncthreads();
    }
    if (t == 0) psum[b] = red[0];
}

__global__ void scanblk_k(int* __restrict__ psum) {
    __shared__ int sc[256];
    int t = threadIdx.x;
    int v = (t < SCB) ? psum[t] : 0;
    sc[t] = v; __syncthreads();
    for (int o = 1; o < 256; o <<= 1) {
        int x = (t >= o) ? sc[t - o] : 0;
        __syncthreads(); sc[t] += x; __syncthreads();
    }
    if (t < SCB) psum[t] = sc[t] - v;   // exclusive
}

__global__ void scanfin_k(const int* __restrict__ hist, const int* __restrict__ psum,
                          int* __restrict__ rowptr) {
    __shared__ int sc[256];
    int b = blockIdx.x, t = threadIdx.x, i = b * 256 + t;
    int v = (i < NN) ? hist[i] : 0;
    sc[t] = v; __syncthreads();
    for (int o = 1; o < 256; o <<= 1) {
        int x = (t >= o) ? sc[t - o] : 0;
        __syncthreads(); sc[t] += x; __syncthreads();
    }
    if (i < NN) rowptr[i] = psum[b] + sc[t] - v;
    if (i == NN - 1) rowptr[NN] = psum[b] + sc[t];
}

__global__ void copyi_k(const int* __restrict__ src, int* __restrict__ dst, int n) {
    int i = blockIdx.x * blockDim.x + threadIdx.x;
    if (i < n) dst[i] = src[i];
}

__global__ void scatter_k(const int* __restrict__ dst, int* __restrict__ next,
                          int* __restrict__ perm) {
    int e = blockIdx.x * blockDim.x + threadIdx.x;
    if (e < NE) {
        int p = atomicAdd(&next[dst[e]], 1);
        perm[p] = e;
    }
}

__global__ void permsd_k(const int* __restrict__ eidx, const int* __restrict__ perm,
                         int* __restrict__ srcS, int* __restrict__ dstS) {
    int i = blockIdx.x * blockDim.x + threadIdx.x;
    if (i < NE) {
        int e = perm[i];
        srcS[i] = eidx[e];
        dstS[i] = eidx[NE + e];
    }
}

// ---- graph pooling counts ----

__global__ void zcnt_k(int* __restrict__ cnts) {
    if (threadIdx.x < NG) cnts[threadIdx.x] = 0;
}

__global__ void count_k(const int* __restrict__ batch, int* __restrict__ cnts) {
    int i = blockIdx.x * blockDim.x + threadIdx.x;
    if (i < NN) atomicAdd(&cnts[batch[i]], 1);
}

__global__ void fc_k(const float* __restrict__ pooled, const int* __restrict__ cnts,
                     const float* __restrict__ W1, const float* __restrict__ b1,
                     const float* __restrict__ W4, const float* __restrict__ b4,
                     float* __restrict__ out) {
    __shared__ float pl[NL * HD];
    __shared__ float hm[HD];
    int g = blockIdx.x, t = threadIdx.x;
    const float inv = 1.0f / fmaxf((float)cnts[g], 1.0f);
#pragma unroll
    for (int j = 0; j < 4; ++j)
        pl[t + j * 256] = pooled[(size_t)g * 1024 + t + j * 256] * inv;
    __syncthreads();
    float a = b1[t];
    for (int k = 0; k < 1024; ++k) a += pl[k] * W1[k * 256 + t];
    hm[t] = a > 0.0f ? a : 0.0f;
    __syncthreads();
    if (t < OD) {
        float o = b4[t];
        for (int k = 0; k < 256; ++k) o += hm[k] * W4[k * OD + t];
        out[g * OD + t] = o;
    }
}

// ---------------------------------------------------------------------------

extern "C" void kernel_launch(void* const* d_in, const int* in_sizes, int n_in,
                              void* d_out, int out_size, void* d_ws, size_t ws_size,
                              hipStream_t stream) {
    const float* x_in  = (const float*)d_in[0];
    const int*   eidx  = (const int*)d_in[1];
    const float* eattr = (const float*)d_in[2];
    const int*   batch = (const int*)d_in[3];
    const float* bW1   = (const float*)d_in[4];
    const float* bb1   = (const float*)d_in[5];
    const float* bW2   = (const float*)d_in[6];
    const float* bb2   = (const float*)d_in[7];
    const float* mW1   = (const float*)d_in[8];
    const float* mb1   = (const float*)d_in[9];
    const float* mW2   = (const float*)d_in[10];
    const float* mb2   = (const float*)d_in[11];
    const float* epsv  = (const float*)d_in[12];
    const float* gamma = (const float*)d_in[13];
    const float* beta  = (const float*)d_in[14];
    const float* fc1W  = (const float*)d_in[15];
    const float* fc1b  = (const float*)d_in[16];
    const float* fc4W  = (const float*)d_in[17];
    const float* fc4b  = (const float*)d_in[18];
    float* out = (float*)d_out;
    (void)in_sizes; (void)n_in; (void)out_size; (void)ws_size;

    // ---- workspace carve (~148 MB; ~156 MB proven safe) ----
    size_t off = 0;
    auto alloc = [&](size_t bytes) -> char* {
        char* r = (char*)d_ws + off;
        off = (off + bytes + 255) & ~(size_t)255;
        return r;
    };
    u16*   xh   = (u16*)alloc((size_t)NN * HD * 2);    // 25.6 MB node feats, fp16
    float* aggr = (float*)alloc((size_t)NN * HD * 4);  // 51.2 MB aggregate, fp32
    u16*   hb   = (u16*)alloc((size_t)NN * HD * 2);    // 25.6 MB MLP out pre-BN
    u16*   eattrS = (u16*)alloc((size_t)NE * FEA * 2); // 38.4 MB sorted fp16 eattr
    u16*   W1t  = (u16*)alloc((size_t)NL * FEA * HD * 2);
    u16*   W2t  = (u16*)alloc((size_t)NL * HD * HD * 2);
    u16*   M1t  = (u16*)alloc((size_t)NL * HD * HD * 2);
    u16*   M2t  = (u16*)alloc((size_t)NL * HD * HD * 2);
    float* bns  = (float*)alloc(HD * 4);
    float* bnq  = (float*)alloc(HD * 4);
    float* ab   = (float*)alloc(2 * HD * 4);
    int*   cnts = (int*)alloc(NG * 4);
    float* pooled = (float*)alloc((size_t)NG * NL * HD * 4);
    int*   hist  = (int*)alloc((size_t)NN * 4);        // also reused as `next`
    int*   psum  = (int*)alloc((size_t)SCB * 4);
    int*   rowptr = (int*)alloc((size_t)(NN + 1) * 4);
    int*   perm  = (int*)alloc((size_t)NE * 4);
    int*   srcS  = (int*)alloc((size_t)NE * 4);
    int*   dstS  = (int*)alloc((size_t)NE * 4);

    const int NEL = NN * HD;
    const int EB = (NEL + 255) / 256;
    const int EB4 = (NEL / 4 + 255) / 256;
    const int NEB = (NE + 255) / 256;

    // weights: fp32 -> fp16, transposed to [N,K]
    transpose_k<<<(NL * FEA * HD + 255) / 256, 256, 0, stream>>>(bW1, W1t, FEA, HD);
    transpose_k<<<(NL * HD * HD + 255) / 256, 256, 0, stream>>>(bW2, W2t, HD, HD);
    transpose_k<<<(NL * HD * HD + 255) / 256, 256, 0, stream>>>(mW1, M1t, HD, HD);
    transpose_k<<<(NL * HD * HD + 255) / 256, 256, 0, stream>>>(mW2, M2t, HD, HD);

    cvt_k<<<EB, 256, 0, stream>>>(x_in, xh, NEL);

    // counting-sort edges by dst: hist -> hierarchical scan -> scatter perm
    zeroi_k<<<(NN + 255) / 256, 256, 0, stream>>>(hist, NN);
    hist_k<<<NEB, 256, 0, stream>>>(eidx + NE, hist);
    sumblk_k<<<SCB, 256, 0, stream>>>(hist, psum);
    scanblk_k<<<1, 256, 0, stream>>>(psum);
    scanfin_k<<<SCB, 256, 0, stream>>>(hist, psum, rowptr);
    copyi_k<<<(NN + 255) / 256, 256, 0, stream>>>(rowptr, hist, NN);   // hist = next
    scatter_k<<<NEB, 256, 0, stream>>>(eidx + NE, hist, perm);
    permsd_k<<<NEB, 256, 0, stream>>>(eidx, perm, srcS, dstS);
    egather_k<<<(NE * FEA + 255) / 256, 256, 0, stream>>>(eattr, perm, eattrS);

    zcnt_k<<<1, 256, 0, stream>>>(cnts);
    count_k<<<(NN + 255) / 256, 256, 0, stream>>>(batch, cnts);
    zerof_k<<<(NG * NL * HD + 255) / 256, 256, 0, stream>>>(pooled, NG * NL * HD);

    // initial zero of aggr + bn accumulators (later layers zeroed in
    // bnapply_k / bnfin_k respectively)
    zero_layer_k<<<EB4, 256, 0, stream>>>((float4*)aggr, bns, bnq);

    const int NGB = (NN + 63) / 64;    // 782 node blocks

    for (int l = 0; l < NL; ++l) {
        edge_k<<<EBLK, 256, 0, stream>>>(
            eattrS, W1t + (size_t)l * FEA * HD, bb1 + l * HD,
            W2t + (size_t)l * HD * HD, bb2 + l * HD,
            srcS, dstS, xh, aggr);
        node_k<<<NGB, 256, 0, stream>>>(
            xh, aggr, epsv, l,
            M1t + (size_t)l * HD * HD, mb1 + l * HD,
            M2t + (size_t)l * HD * HD, mb2 + l * HD,
            hb, bns, bnq);
        bnfin_k<<<1, HD, 0, stream>>>(bns, bnq, gamma, beta, l, ab);
        bnapply_k<<<NGB, 256, 0, stream>>>(hb, ab, batch, xh, pooled, l,
                                           aggr, (l < NL - 1) ? 1 : 0);
    }
    fc_k<<<NG, 256, 0, stream>>>(pooled, cnts, fc1W, fc1b, fc4W, fc4b, out);
}